// Round 2
// baseline (183.857 us; speedup 1.0000x reference)
//
#include <hip/hip_runtime.h>

#define NG 4096
#define RELAX 0.1875f
#define CHUNK 256
#define EV_THREADS 256
#define EV_GRID 2048

__device__ __forceinline__ float linf(int i) { return -1.0f + (2.0f/63.0f)*(float)i; }
// center-first axis permutation: {7,8,6,9,5,10,4,11,3,12,2,13,1,14,0,15}
__device__ __forceinline__ int cperm(int i) { return (i & 1) ? 7 + ((i+1)>>1) : 7 - (i>>1); }

// ======================================================================
// A: fused reduce + transform + 3D binning.  256 blocks x 256 threads.
// Each block:
//   phase 1: redundant masked min/max over all 4096 (L2-resident, identical
//            result per block -> bit-identical center/scale everywhere)
//   phase 2: transform its own slice of 16 gaussians -> posopa/invrec
//   phase 3: bin its (bi,bj)=blockIdx column: window test from raw xyz
//            (same float expressions as phase 2 -> bit-identical coords),
//            z-bin range cut to ~6 candidates analytically, exact predicate.
// Also resets the eval work-queue counter.
// ======================================================================
__global__ __launch_bounds__(256) void gm_prep_bin(
    const float* __restrict__ xyz, const float* __restrict__ scal,
    const float* __restrict__ rot, const float* __restrict__ opac,
    float4* __restrict__ posopa, float4* __restrict__ invrec,
    int* __restrict__ bincnt, unsigned short* __restrict__ binidx, int cap,
    int* __restrict__ qctr)
{
  __shared__ float s_mn[3][256];
  __shared__ float s_mx[3][256];
  __shared__ int   s_cnt[16];
  const int tid = threadIdx.x;
  const int b   = blockIdx.x;            // bi*16 + bj
  if (b == 0 && tid == 0) *qctr = 0;     // stream-ordered: prev eval is done

  // ---- phase 1: masked min/max ----
  float mn0=1e10f, mn1=1e10f, mn2=1e10f;
  float mx0=-1e10f, mx1=-1e10f, mx2=-1e10f;
  #pragma unroll
  for (int t = 0; t < NG/256; ++t) {
    int g = t*256 + tid;
    float o = opac[g];
    float sig = 1.0f/(1.0f + __expf(-o));
    bool keep = sig > 0.005f;
    float x = xyz[3*g+0], y = xyz[3*g+1], z = xyz[3*g+2];
    if (keep) {
      mn0 = fminf(mn0, x); mn1 = fminf(mn1, y); mn2 = fminf(mn2, z);
      mx0 = fmaxf(mx0, x); mx1 = fmaxf(mx1, y); mx2 = fmaxf(mx2, z);
    }
  }
  s_mn[0][tid]=mn0; s_mn[1][tid]=mn1; s_mn[2][tid]=mn2;
  s_mx[0][tid]=mx0; s_mx[1][tid]=mx1; s_mx[2][tid]=mx2;
  __syncthreads();
  for (int s = 128; s > 0; s >>= 1) {
    if (tid < s) {
      #pragma unroll
      for (int k = 0; k < 3; ++k) {
        s_mn[k][tid] = fminf(s_mn[k][tid], s_mn[k][tid+s]);
        s_mx[k][tid] = fmaxf(s_mx[k][tid], s_mx[k][tid+s]);
      }
    }
    __syncthreads();
  }
  const float cx = (s_mn[0][0]+s_mx[0][0])*0.5f;
  const float cy = (s_mn[1][0]+s_mx[1][0])*0.5f;
  const float cz = (s_mn[2][0]+s_mx[2][0])*0.5f;
  const float rmax = fmaxf(s_mx[0][0]-s_mn[0][0],
                     fmaxf(s_mx[1][0]-s_mn[1][0], s_mx[2][0]-s_mn[2][0]));
  const float sc = 1.8f/rmax;

  // ---- phase 2: transform my slice of 16 gaussians ----
  if (tid < 16) {
    const int g = b*16 + tid;
    float o = opac[g];
    float sig = 1.0f/(1.0f + __expf(-o));
    float opa = (sig > 0.005f) ? sig : 0.0f;
    float xs = (xyz[3*g+0]-cx)*sc;
    float ys = (xyz[3*g+1]-cy)*sc;
    float zs = (xyz[3*g+2]-cz)*sc;
    float sdx = __expf(scal[3*g+0])*sc;
    float sdy = __expf(scal[3*g+1])*sc;
    float sdz = __expf(scal[3*g+2])*sc;
    float qr=rot[4*g+0], qx=rot[4*g+1], qy=rot[4*g+2], qz=rot[4*g+3];
    float qn = 1.0f/sqrtf(qr*qr+qx*qx+qy*qy+qz*qz);
    qr*=qn; qx*=qn; qy*=qn; qz*=qn;
    float R00 = 1.0f-2.0f*(qy*qy+qz*qz), R01 = 2.0f*(qx*qy-qr*qz), R02 = 2.0f*(qx*qz+qr*qy);
    float R10 = 2.0f*(qx*qy+qr*qz), R11 = 1.0f-2.0f*(qx*qx+qz*qz), R12 = 2.0f*(qy*qz-qr*qx);
    float R20 = 2.0f*(qx*qz-qr*qy), R21 = 2.0f*(qy*qz+qr*qx), R22 = 1.0f-2.0f*(qx*qx+qy*qy);
    float L00=R00*sdx, L01=R01*sdy, L02=R02*sdz;
    float L10=R10*sdx, L11=R11*sdy, L12=R12*sdz;
    float L20=R20*sdx, L21=R21*sdy, L22=R22*sdz;
    float a = L00*L00+L01*L01+L02*L02;
    float bb= L00*L10+L01*L11+L02*L12;
    float cc= L00*L20+L01*L21+L02*L22;
    float d = L10*L10+L11*L11+L12*L12;
    float e = L10*L20+L11*L21+L12*L22;
    float f = L20*L20+L21*L21+L22*L22;
    float det = a*d*f + 2.0f*e*cc*bb - e*e*a - cc*cc*d - bb*bb*f + 1e-24f;
    float idt = 1.0f/det;
    float ia=(d*f-e*e)*idt, ib=(e*cc-bb*f)*idt, ic=(e*bb-cc*d)*idt;
    float id=(a*f-cc*cc)*idt, ie=(bb*cc-e*a)*idt, iff=(a*d-bb*bb)*idt;
    posopa[g] = make_float4(xs, ys, zs, opa);
    invrec[2*g+0] = make_float4(-0.5f*ia, -ib, -ic, -0.5f*id);
    invrec[2*g+1] = make_float4(-ie, -0.5f*iff, 0.0f, 0.0f);
  }

  // ---- phase 3: bin my (bi,bj) column ----
  const int bi = b >> 4, bj = b & 15;
  const float vminx = linf(bi*4) - RELAX, vmaxx = linf(bi*4+3) + RELAX;
  const float vminy = linf(bj*4) - RELAX, vmaxy = linf(bj*4+3) + RELAX;
  if (tid < 16) s_cnt[tid] = 0;
  __syncthreads();
  #pragma unroll
  for (int t = 0; t < NG/256; ++t) {
    int g = t*256 + tid;
    float o = opac[g];
    float sig = 1.0f/(1.0f + __expf(-o));
    if (!(sig > 0.005f)) continue;                 // opa == 0 -> contributes 0
    float xs = (xyz[3*g+0]-cx)*sc;                 // same exprs as phase 2
    float ys = (xyz[3*g+1]-cy)*sc;
    float zs = (xyz[3*g+2]-cz)*sc;
    if (xs > vminx && xs < vmaxx && ys > vminy && ys < vmaxy) {
      // analytic z-bin range (conservative), exact predicate inside
      int klo = (int)floorf(((zs + 0.8125f)*31.5f - 3.0f)*0.25f) - 1;
      int khi = (int)floorf((zs + 1.1875f)*7.875f) + 1;
      klo = max(klo, 0); khi = min(khi, 15);
      for (int bk = klo; bk <= khi; ++bk) {
        float lo = linf(bk*4) - RELAX, hi = linf(bk*4+3) + RELAX;
        if (zs > lo && zs < hi) {
          int slot = atomicAdd(&s_cnt[bk], 1);
          if (slot < cap)
            binidx[(size_t)((b<<4) + bk)*cap + slot] = (unsigned short)g;
        }
      }
    }
  }
  __syncthreads();
  if (tid < 16) bincnt[(b<<4) + tid] = min(s_cnt[tid], cap);
}

// ======================================================================
// B: eval with dynamic bin queue (center-first / heaviest-first pop order).
// 2048 blocks x 256 threads (4 waves; part = tid>>6 in 0..3).
// ======================================================================
__global__ __launch_bounds__(EV_THREADS) void gm_evaluate(
    const float4* __restrict__ posopa, const float4* __restrict__ invrec,
    const int* __restrict__ bincnt, const unsigned short* __restrict__ binidx,
    int cap, int* __restrict__ qctr, float* __restrict__ out)
{
  __shared__ float4 s_g[CHUNK*3];       // 12 KB
  __shared__ float  s_acc[EV_THREADS];  //  1 KB
  __shared__ int    s_q;
  const int tid  = threadIdx.x;
  const int p    = tid & 63;
  const int part = tid >> 6;            // 0..3
  const int sx = p >> 4, sy = (p >> 2) & 3, sz = p & 3;

  for (;;) {
    if (tid == 0) s_q = atomicAdd(qctr, 1);
    __syncthreads();                    // (A) publishes s_q; fences s_acc reuse
    const int q = s_q;
    if (q >= 4096) break;
    const int bi = cperm(q >> 8), bj = cperm((q >> 4) & 15), bk = cperm(q & 15);
    const int bin = (bi*16 + bj)*16 + bk;
    const float ptx = linf(bi*4+sx), pty = linf(bj*4+sy), ptz = linf(bk*4+sz);
    const unsigned short* mylist = binidx + (size_t)bin*cap;
    const int n = bincnt[bin];
    float acc = 0.0f;

    for (int c0 = 0; c0 < n; c0 += CHUNK) {
      __syncthreads();                  // protect s_g from prev chunk readers
      const int lim = min(n - c0, CHUNK);
      if (tid < lim) {                  // EV_THREADS == CHUNK: 1 record/thread
        int g = mylist[c0 + tid];
        s_g[3*tid+0] = posopa[g];
        s_g[3*tid+1] = invrec[2*g+0];
        s_g[3*tid+2] = invrec[2*g+1];
      }
      __syncthreads();
      #pragma unroll 4
      for (int j = part; j < lim; j += 4) {
        float4 P  = s_g[3*j+0];
        float4 I0 = s_g[3*j+1];
        float4 I1 = s_g[3*j+2];
        float px = ptx - P.x, py = pty - P.y, pz = ptz - P.z;
        float power = px*px*I0.x + py*py*I0.w + pz*pz*I1.y
                    + px*py*I0.y + px*pz*I0.z + py*pz*I1.x;
        power = (power > 0.0f) ? -1e10f : power;   // branchless
        acc += P.w * __expf(power);
      }
    }

    s_acc[tid] = acc;
    __syncthreads();
    if (tid < 64) {
      float v = 0.0f;
      #pragma unroll
      for (int w = 0; w < 4; ++w) v += s_acc[tid + w*64];
      out[(bi*4+sx)*4096 + (bj*4+sy)*64 + (bk*4+sz)] = v;
    }
    // next iteration's barrier (A) orders these reads vs next s_acc writes
  }
}

// ======================================================================
// Fallback path (ws too small for 3D bins): fused prep + brute-force eval
// ======================================================================
__global__ __launch_bounds__(512) void gm_prep(
    const float* __restrict__ xyz, const float* __restrict__ scal,
    const float* __restrict__ rot, const float* __restrict__ opac,
    float4* __restrict__ posopa, float4* __restrict__ invrec)
{
  __shared__ float s_mn[3][512];
  __shared__ float s_mx[3][512];
  const int tid = threadIdx.x;
  float mn0=1e10f, mn1=1e10f, mn2=1e10f;
  float mx0=-1e10f, mx1=-1e10f, mx2=-1e10f;
  #pragma unroll
  for (int t = 0; t < NG/512; ++t) {
    int g = t*512 + tid;
    float o = opac[g];
    float sig = 1.0f/(1.0f + __expf(-o));
    bool keep = sig > 0.005f;
    float x = xyz[3*g+0], y = xyz[3*g+1], z = xyz[3*g+2];
    if (keep) {
      mn0 = fminf(mn0, x); mn1 = fminf(mn1, y); mn2 = fminf(mn2, z);
      mx0 = fmaxf(mx0, x); mx1 = fmaxf(mx1, y); mx2 = fmaxf(mx2, z);
    }
  }
  s_mn[0][tid]=mn0; s_mn[1][tid]=mn1; s_mn[2][tid]=mn2;
  s_mx[0][tid]=mx0; s_mx[1][tid]=mx1; s_mx[2][tid]=mx2;
  __syncthreads();
  for (int s = 256; s > 0; s >>= 1) {
    if (tid < s) {
      #pragma unroll
      for (int k = 0; k < 3; ++k) {
        s_mn[k][tid] = fminf(s_mn[k][tid], s_mn[k][tid+s]);
        s_mx[k][tid] = fmaxf(s_mx[k][tid], s_mx[k][tid+s]);
      }
    }
    __syncthreads();
  }
  const float cx = (s_mn[0][0]+s_mx[0][0])*0.5f;
  const float cy = (s_mn[1][0]+s_mx[1][0])*0.5f;
  const float cz = (s_mn[2][0]+s_mx[2][0])*0.5f;
  const float rmax = fmaxf(s_mx[0][0]-s_mn[0][0],
                     fmaxf(s_mx[1][0]-s_mn[1][0], s_mx[2][0]-s_mn[2][0]));
  const float sc = 1.8f/rmax;

  const int g = blockIdx.x*512 + tid;
  float o = opac[g];
  float sig = 1.0f/(1.0f + __expf(-o));
  float opa = (sig > 0.005f) ? sig : 0.0f;
  float xs = (xyz[3*g+0]-cx)*sc;
  float ys = (xyz[3*g+1]-cy)*sc;
  float zs = (xyz[3*g+2]-cz)*sc;
  float sdx = __expf(scal[3*g+0])*sc;
  float sdy = __expf(scal[3*g+1])*sc;
  float sdz = __expf(scal[3*g+2])*sc;
  float qr=rot[4*g+0], qx=rot[4*g+1], qy=rot[4*g+2], qz=rot[4*g+3];
  float qn = 1.0f/sqrtf(qr*qr+qx*qx+qy*qy+qz*qz);
  qr*=qn; qx*=qn; qy*=qn; qz*=qn;
  float R00 = 1.0f-2.0f*(qy*qy+qz*qz), R01 = 2.0f*(qx*qy-qr*qz), R02 = 2.0f*(qx*qz+qr*qy);
  float R10 = 2.0f*(qx*qy+qr*qz), R11 = 1.0f-2.0f*(qx*qx+qz*qz), R12 = 2.0f*(qy*qz-qr*qx);
  float R20 = 2.0f*(qx*qz-qr*qy), R21 = 2.0f*(qy*qz+qr*qx), R22 = 1.0f-2.0f*(qx*qx+qy*qy);
  float L00=R00*sdx, L01=R01*sdy, L02=R02*sdz;
  float L10=R10*sdx, L11=R11*sdy, L12=R12*sdz;
  float L20=R20*sdx, L21=R21*sdy, L22=R22*sdz;
  float a = L00*L00+L01*L01+L02*L02;
  float b = L00*L10+L01*L11+L02*L12;
  float cc= L00*L20+L01*L21+L02*L22;
  float d = L10*L10+L11*L11+L12*L12;
  float e = L10*L20+L11*L21+L12*L22;
  float f = L20*L20+L21*L21+L22*L22;
  float det = a*d*f + 2.0f*e*cc*b - e*e*a - cc*cc*d - b*b*f + 1e-24f;
  float idt = 1.0f/det;
  float ia=(d*f-e*e)*idt, ib=(e*cc-b*f)*idt, ic=(e*b-cc*d)*idt;
  float id=(a*f-cc*cc)*idt, ie=(b*cc-e*a)*idt, iff=(a*d-b*b)*idt;
  posopa[g] = make_float4(xs, ys, zs, opa);
  invrec[2*g+0] = make_float4(-0.5f*ia, -ib, -ic, -0.5f*id);
  invrec[2*g+1] = make_float4(-ie, -0.5f*iff, 0.0f, 0.0f);
}

__global__ __launch_bounds__(512) void gm_evaluate_nobin(
    const float4* __restrict__ posopa, const float4* __restrict__ invrec,
    float* __restrict__ out)
{
  __shared__ int    s_cnt;
  __shared__ float4 s_g[512*3];
  __shared__ float  s_acc[512];
  const int tid = threadIdx.x;
  const int b = blockIdx.x;
  const int bi = cperm(b >> 8), bj = cperm((b >> 4) & 15), bk = cperm(b & 15);
  const float vminx = linf(bi*4) - RELAX, vmaxx = linf(bi*4+3) + RELAX;
  const float vminy = linf(bj*4) - RELAX, vmaxy = linf(bj*4+3) + RELAX;
  const float vminz = linf(bk*4) - RELAX, vmaxz = linf(bk*4+3) + RELAX;
  const int p    = tid & 63;
  const int part = tid >> 6;
  const int sx = p >> 4, sy = (p >> 2) & 3, sz = p & 3;
  const float ptx = linf(bi*4+sx), pty = linf(bj*4+sy), ptz = linf(bk*4+sz);
  float acc = 0.0f;
  for (int c0 = 0; c0 < NG; c0 += 512) {
    if (tid == 0) s_cnt = 0;
    __syncthreads();
    int g = c0 + tid;
    float4 P = posopa[g];
    if (P.w > 0.0f &&
        P.x > vminx && P.x < vmaxx &&
        P.y > vminy && P.y < vmaxy &&
        P.z > vminz && P.z < vmaxz) {
      int slot = atomicAdd(&s_cnt, 1);
      s_g[3*slot+0] = P;
      s_g[3*slot+1] = invrec[2*g+0];
      s_g[3*slot+2] = invrec[2*g+1];
    }
    __syncthreads();
    const int n = s_cnt;
    #pragma unroll 4
    for (int j = part; j < n; j += 8) {
      float4 Pq = s_g[3*j+0];
      float4 I0 = s_g[3*j+1];
      float4 I1 = s_g[3*j+2];
      float px = ptx - Pq.x, py = pty - Pq.y, pz = ptz - Pq.z;
      float power = px*px*I0.x + py*py*I0.w + pz*pz*I1.y
                  + px*py*I0.y + px*pz*I0.z + py*pz*I1.x;
      power = (power > 0.0f) ? -1e10f : power;
      acc += Pq.w * __expf(power);
    }
    __syncthreads();
  }
  s_acc[tid] = acc;
  __syncthreads();
  if (tid < 64) {
    float v = 0.0f;
    #pragma unroll
    for (int w = 0; w < 8; ++w) v += s_acc[tid + w*64];
    out[(bi*4+sx)*4096 + (bj*4+sy)*64 + (bk*4+sz)] = v;
  }
}

extern "C" void kernel_launch(void* const* d_in, const int* in_sizes, int n_in,
                              void* d_out, int out_size, void* d_ws, size_t ws_size,
                              hipStream_t stream) {
  const float* xyz  = (const float*)d_in[0];
  const float* scal = (const float*)d_in[1];
  const float* rot  = (const float*)d_in[2];
  const float* opac = (const float*)d_in[3];
  float* out = (float*)d_out;
  char* ws = (char*)d_ws;
  float4* posopa = (float4*)(ws);                       //  64 KB
  float4* invrec = (float4*)(ws + 65536);               // 128 KB
  int*    bincnt = (int*)(ws + 65536 + 131072);         //  16 KB (4096 bins)
  int*    qctr   = (int*)(ws + 65536 + 131072 + 16384); //  queue counter (+pad)
  unsigned short* binidx = (unsigned short*)(ws + 65536 + 131072 + 16384 + 256);
  const size_t base = 65536 + 131072 + 16384 + 256;

  int cap = 0;  // per-3D-bin capacity tier; 4096 can never overflow
  if      (ws_size >= base + (size_t)4096*4096*2) cap = 4096;
  else if (ws_size >= base + (size_t)4096*2048*2) cap = 2048;  // max real bin ~1.2K

  if (cap) {
    gm_prep_bin<<<256, 256, 0, stream>>>(xyz, scal, rot, opac,
                                         posopa, invrec, bincnt, binidx, cap, qctr);
    gm_evaluate<<<EV_GRID, EV_THREADS, 0, stream>>>(posopa, invrec,
                                         bincnt, binidx, cap, qctr, out);
  } else {
    gm_prep<<<8, 512, 0, stream>>>(xyz, scal, rot, opac, posopa, invrec);
    gm_evaluate_nobin<<<4096, 512, 0, stream>>>(posopa, invrec, out);
  }
}

// Round 3
// 169.724 us; speedup vs baseline: 1.0833x; 1.0833x over previous
//
#include <hip/hip_runtime.h>

#define NG 4096
#define RELAX 0.1875f
#define KEEPTH -5.2933049f   // logit(0.005): sigmoid(o)>0.005 <=> o>KEEPTH
#define CHUNK 512
#define EV_THREADS 512
#define EV_BLOCKS 512
#define CAP 2048

__device__ __forceinline__ float linf(int i) { return -1.0f + (2.0f/63.0f)*(float)i; }
// center-first axis permutation: {7,8,6,9,5,10,4,11,3,12,2,13,1,14,0,15}
__device__ __forceinline__ int cperm(int i) { return (i & 1) ? 7 + ((i+1)>>1) : 7 - (i>>1); }

// ======================================================================
// A: fused reduce + transform + 3D binning.  256 blocks x 256 threads.
//  phase 1: redundant masked min/max, exp-free keep test, float4 loads
//  phase 2: transform own 16-gaussian slice -> posopa/invrec
//  phase 3: bin own (bi,bj) column, analytic z-range + exact predicate
// ======================================================================
__global__ __launch_bounds__(256) void gm_prep_bin(
    const float* __restrict__ xyz, const float* __restrict__ scal,
    const float* __restrict__ rot, const float* __restrict__ opac,
    float4* __restrict__ posopa, float4* __restrict__ invrec,
    int* __restrict__ bincnt, unsigned short* __restrict__ binidx)
{
  __shared__ float s_r[4][6];
  __shared__ int   s_cnt[16];
  const int tid = threadIdx.x;
  const int b   = blockIdx.x;            // bi*16 + bj
  const float4* xyz4 = (const float4*)xyz;
  const float4* op4  = (const float4*)opac;

  // ---- phase 1: masked min/max (exp-free, vectorized) ----
  float mn0=1e10f, mn1=1e10f, mn2=1e10f;
  float mx0=-1e10f, mx1=-1e10f, mx2=-1e10f;
  #pragma unroll
  for (int t = 0; t < 4; ++t) {
    const int G = t*256 + tid;           // group of 4 gaussians
    float4 v0 = xyz4[3*G+0], v1 = xyz4[3*G+1], v2 = xyz4[3*G+2];
    float4 oo = op4[G];
    if (oo.x > KEEPTH) { mn0=fminf(mn0,v0.x); mx0=fmaxf(mx0,v0.x);
                         mn1=fminf(mn1,v0.y); mx1=fmaxf(mx1,v0.y);
                         mn2=fminf(mn2,v0.z); mx2=fmaxf(mx2,v0.z); }
    if (oo.y > KEEPTH) { mn0=fminf(mn0,v0.w); mx0=fmaxf(mx0,v0.w);
                         mn1=fminf(mn1,v1.x); mx1=fmaxf(mx1,v1.x);
                         mn2=fminf(mn2,v1.y); mx2=fmaxf(mx2,v1.y); }
    if (oo.z > KEEPTH) { mn0=fminf(mn0,v1.z); mx0=fmaxf(mx0,v1.z);
                         mn1=fminf(mn1,v1.w); mx1=fmaxf(mx1,v1.w);
                         mn2=fminf(mn2,v2.x); mx2=fmaxf(mx2,v2.x); }
    if (oo.w > KEEPTH) { mn0=fminf(mn0,v2.y); mx0=fmaxf(mx0,v2.y);
                         mn1=fminf(mn1,v2.z); mx1=fmaxf(mx1,v2.z);
                         mn2=fminf(mn2,v2.w); mx2=fmaxf(mx2,v2.w); }
  }
  #pragma unroll
  for (int s = 1; s < 64; s <<= 1) {
    mn0 = fminf(mn0, __shfl_xor(mn0, s)); mx0 = fmaxf(mx0, __shfl_xor(mx0, s));
    mn1 = fminf(mn1, __shfl_xor(mn1, s)); mx1 = fmaxf(mx1, __shfl_xor(mx1, s));
    mn2 = fminf(mn2, __shfl_xor(mn2, s)); mx2 = fmaxf(mx2, __shfl_xor(mx2, s));
  }
  if ((tid & 63) == 0) {
    const int w = tid >> 6;
    s_r[w][0]=mn0; s_r[w][1]=mn1; s_r[w][2]=mn2;
    s_r[w][3]=mx0; s_r[w][4]=mx1; s_r[w][5]=mx2;
  }
  if (tid < 16) s_cnt[tid] = 0;
  __syncthreads();
  mn0 = fminf(fminf(s_r[0][0],s_r[1][0]), fminf(s_r[2][0],s_r[3][0]));
  mn1 = fminf(fminf(s_r[0][1],s_r[1][1]), fminf(s_r[2][1],s_r[3][1]));
  mn2 = fminf(fminf(s_r[0][2],s_r[1][2]), fminf(s_r[2][2],s_r[3][2]));
  mx0 = fmaxf(fmaxf(s_r[0][3],s_r[1][3]), fmaxf(s_r[2][3],s_r[3][3]));
  mx1 = fmaxf(fmaxf(s_r[0][4],s_r[1][4]), fmaxf(s_r[2][4],s_r[3][4]));
  mx2 = fmaxf(fmaxf(s_r[0][5],s_r[1][5]), fmaxf(s_r[2][5],s_r[3][5]));
  const float cx = (mn0+mx0)*0.5f;
  const float cy = (mn1+mx1)*0.5f;
  const float cz = (mn2+mx2)*0.5f;
  const float sc = 1.8f/fmaxf(mx0-mn0, fmaxf(mx1-mn1, mx2-mn2));

  // ---- phase 2: transform my 16-gaussian slice ----
  if (tid < 16) {
    const int g = b*16 + tid;
    float o = opac[g];
    float sig = 1.0f/(1.0f + __expf(-o));
    float opa = (sig > 0.005f) ? sig : 0.0f;
    float xs = (xyz[3*g+0]-cx)*sc;
    float ys = (xyz[3*g+1]-cy)*sc;
    float zs = (xyz[3*g+2]-cz)*sc;
    float sdx = __expf(scal[3*g+0])*sc;
    float sdy = __expf(scal[3*g+1])*sc;
    float sdz = __expf(scal[3*g+2])*sc;
    float qr=rot[4*g+0], qx=rot[4*g+1], qy=rot[4*g+2], qz=rot[4*g+3];
    float qn = 1.0f/sqrtf(qr*qr+qx*qx+qy*qy+qz*qz);
    qr*=qn; qx*=qn; qy*=qn; qz*=qn;
    float R00 = 1.0f-2.0f*(qy*qy+qz*qz), R01 = 2.0f*(qx*qy-qr*qz), R02 = 2.0f*(qx*qz+qr*qy);
    float R10 = 2.0f*(qx*qy+qr*qz), R11 = 1.0f-2.0f*(qx*qx+qz*qz), R12 = 2.0f*(qy*qz-qr*qx);
    float R20 = 2.0f*(qx*qz-qr*qy), R21 = 2.0f*(qy*qz+qr*qx), R22 = 1.0f-2.0f*(qx*qx+qy*qy);
    float L00=R00*sdx, L01=R01*sdy, L02=R02*sdz;
    float L10=R10*sdx, L11=R11*sdy, L12=R12*sdz;
    float L20=R20*sdx, L21=R21*sdy, L22=R22*sdz;
    float a = L00*L00+L01*L01+L02*L02;
    float bb= L00*L10+L01*L11+L02*L12;
    float cc= L00*L20+L01*L21+L02*L22;
    float d = L10*L10+L11*L11+L12*L12;
    float e = L10*L20+L11*L21+L12*L22;
    float f = L20*L20+L21*L21+L22*L22;
    float det = a*d*f + 2.0f*e*cc*bb - e*e*a - cc*cc*d - bb*bb*f + 1e-24f;
    float idt = 1.0f/det;
    float ia=(d*f-e*e)*idt, ib=(e*cc-bb*f)*idt, ic=(e*bb-cc*d)*idt;
    float id=(a*f-cc*cc)*idt, ie=(bb*cc-e*a)*idt, iff=(a*d-bb*bb)*idt;
    posopa[g] = make_float4(xs, ys, zs, opa);
    invrec[2*g+0] = make_float4(-0.5f*ia, -ib, -ic, -0.5f*id);
    invrec[2*g+1] = make_float4(-ie, -0.5f*iff, 0.0f, 0.0f);
  }

  // ---- phase 3: bin my (bi,bj) column (exp-free, float4 loads) ----
  const int bi = b >> 4, bj = b & 15;
  const float vminx = linf(bi*4) - RELAX, vmaxx = linf(bi*4+3) + RELAX;
  const float vminy = linf(bj*4) - RELAX, vmaxy = linf(bj*4+3) + RELAX;
  #pragma unroll
  for (int t = 0; t < 4; ++t) {
    const int G = t*256 + tid;
    float4 v0 = xyz4[3*G+0], v1 = xyz4[3*G+1], v2 = xyz4[3*G+2];
    float4 oo = op4[G];
    float gx[4] = {v0.x, v0.w, v1.z, v2.y};
    float gy[4] = {v0.y, v1.x, v1.w, v2.z};
    float gz[4] = {v0.z, v1.y, v2.x, v2.w};
    float go[4] = {oo.x, oo.y, oo.z, oo.w};
    #pragma unroll
    for (int u = 0; u < 4; ++u) {
      if (!(go[u] > KEEPTH)) continue;
      float xs = (gx[u]-cx)*sc;                 // same exprs as phase 2
      float ys = (gy[u]-cy)*sc;
      float zs = (gz[u]-cz)*sc;
      if (xs > vminx && xs < vmaxx && ys > vminy && ys < vmaxy) {
        int klo = (int)floorf(((zs + 0.8125f)*31.5f - 3.0f)*0.25f) - 1;
        int khi = (int)floorf((zs + 1.1875f)*7.875f) + 1;
        klo = max(klo, 0); khi = min(khi, 15);
        for (int bk = klo; bk <= khi; ++bk) {
          float lo = linf(bk*4) - RELAX, hi = linf(bk*4+3) + RELAX;
          if (zs > lo && zs < hi) {
            int slot = atomicAdd(&s_cnt[bk], 1);
            if (slot < CAP)
              binidx[(size_t)((b<<4) + bk)*CAP + slot] = (unsigned short)(4*G+u);
          }
        }
      }
    }
  }
  __syncthreads();
  if (tid < 16) bincnt[(b<<4) + tid] = min(s_cnt[tid], CAP);
}

// ======================================================================
// B: eval, static 8-bins-per-block stride in center-first order.
// 512 blocks x 512 threads (8 waves; part = tid>>6 in 0..7).
// ======================================================================
__global__ __launch_bounds__(EV_THREADS) void gm_evaluate(
    const float4* __restrict__ posopa, const float4* __restrict__ invrec,
    const int* __restrict__ bincnt, const unsigned short* __restrict__ binidx,
    float* __restrict__ out)
{
  __shared__ float4 s_g[CHUNK*3];       // 24 KB
  __shared__ float  s_acc[EV_THREADS];  //  2 KB
  const int tid  = threadIdx.x;
  const int p    = tid & 63;
  const int part = tid >> 6;            // 0..7
  const int sx = p >> 4, sy = (p >> 2) & 3, sz = p & 3;

  for (int k = 0; k < 8; ++k) {
    const int q = k*EV_BLOCKS + blockIdx.x;       // heavy-first across blocks
    const int bi = cperm(q >> 8), bj = cperm((q >> 4) & 15), bk = cperm(q & 15);
    const int bin = (bi*16 + bj)*16 + bk;
    const float ptx = linf(bi*4+sx), pty = linf(bj*4+sy), ptz = linf(bk*4+sz);
    const unsigned short* mylist = binidx + (size_t)bin*CAP;
    const int n = bincnt[bin];
    float acc = 0.0f;

    for (int c0 = 0; c0 < n; c0 += CHUNK) {
      __syncthreads();                  // s_g safe to overwrite
      const int lim = min(n - c0, CHUNK);
      if (tid < lim) {                  // EV_THREADS == CHUNK
        int g = mylist[c0 + tid];
        s_g[3*tid+0] = posopa[g];
        s_g[3*tid+1] = invrec[2*g+0];
        s_g[3*tid+2] = invrec[2*g+1];
      }
      __syncthreads();
      #pragma unroll 4
      for (int j = part; j < lim; j += 8) {
        float4 P  = s_g[3*j+0];
        float4 I0 = s_g[3*j+1];
        float4 I1 = s_g[3*j+2];
        float px = ptx - P.x, py = pty - P.y, pz = ptz - P.z;
        float power = px*px*I0.x + py*py*I0.w + pz*pz*I1.y
                    + px*py*I0.y + px*pz*I0.z + py*pz*I1.x;
        power = (power > 0.0f) ? -1e10f : power;   // branchless
        acc += P.w * __expf(power);
      }
    }

    __syncthreads();                    // prev bin's s_acc readers done
    s_acc[tid] = acc;
    __syncthreads();
    if (tid < 64) {
      float v = 0.0f;
      #pragma unroll
      for (int w = 0; w < 8; ++w) v += s_acc[tid + w*64];
      out[(bi*4+sx)*4096 + (bj*4+sy)*64 + (bk*4+sz)] = v;
    }
  }
}

// ======================================================================
// Fallback path (ws too small for 3D bins): prep + brute-force eval
// ======================================================================
__global__ __launch_bounds__(512) void gm_prep(
    const float* __restrict__ xyz, const float* __restrict__ scal,
    const float* __restrict__ rot, const float* __restrict__ opac,
    float4* __restrict__ posopa, float4* __restrict__ invrec)
{
  __shared__ float s_mn[3][512];
  __shared__ float s_mx[3][512];
  const int tid = threadIdx.x;
  float mn0=1e10f, mn1=1e10f, mn2=1e10f;
  float mx0=-1e10f, mx1=-1e10f, mx2=-1e10f;
  #pragma unroll
  for (int t = 0; t < NG/512; ++t) {
    int g = t*512 + tid;
    float o = opac[g];
    bool keep = o > KEEPTH;
    float x = xyz[3*g+0], y = xyz[3*g+1], z = xyz[3*g+2];
    if (keep) {
      mn0 = fminf(mn0, x); mn1 = fminf(mn1, y); mn2 = fminf(mn2, z);
      mx0 = fmaxf(mx0, x); mx1 = fmaxf(mx1, y); mx2 = fmaxf(mx2, z);
    }
  }
  s_mn[0][tid]=mn0; s_mn[1][tid]=mn1; s_mn[2][tid]=mn2;
  s_mx[0][tid]=mx0; s_mx[1][tid]=mx1; s_mx[2][tid]=mx2;
  __syncthreads();
  for (int s = 256; s > 0; s >>= 1) {
    if (tid < s) {
      #pragma unroll
      for (int k = 0; k < 3; ++k) {
        s_mn[k][tid] = fminf(s_mn[k][tid], s_mn[k][tid+s]);
        s_mx[k][tid] = fmaxf(s_mx[k][tid], s_mx[k][tid+s]);
      }
    }
    __syncthreads();
  }
  const float cx = (s_mn[0][0]+s_mx[0][0])*0.5f;
  const float cy = (s_mn[1][0]+s_mx[1][0])*0.5f;
  const float cz = (s_mn[2][0]+s_mx[2][0])*0.5f;
  const float rmax = fmaxf(s_mx[0][0]-s_mn[0][0],
                     fmaxf(s_mx[1][0]-s_mn[1][0], s_mx[2][0]-s_mn[2][0]));
  const float sc = 1.8f/rmax;

  const int g = blockIdx.x*512 + tid;
  float o = opac[g];
  float sig = 1.0f/(1.0f + __expf(-o));
  float opa = (sig > 0.005f) ? sig : 0.0f;
  float xs = (xyz[3*g+0]-cx)*sc;
  float ys = (xyz[3*g+1]-cy)*sc;
  float zs = (xyz[3*g+2]-cz)*sc;
  float sdx = __expf(scal[3*g+0])*sc;
  float sdy = __expf(scal[3*g+1])*sc;
  float sdz = __expf(scal[3*g+2])*sc;
  float qr=rot[4*g+0], qx=rot[4*g+1], qy=rot[4*g+2], qz=rot[4*g+3];
  float qn = 1.0f/sqrtf(qr*qr+qx*qx+qy*qy+qz*qz);
  qr*=qn; qx*=qn; qy*=qn; qz*=qn;
  float R00 = 1.0f-2.0f*(qy*qy+qz*qz), R01 = 2.0f*(qx*qy-qr*qz), R02 = 2.0f*(qx*qz+qr*qy);
  float R10 = 2.0f*(qx*qy+qr*qz), R11 = 1.0f-2.0f*(qx*qx+qz*qz), R12 = 2.0f*(qy*qz-qr*qx);
  float R20 = 2.0f*(qx*qz-qr*qy), R21 = 2.0f*(qy*qz+qr*qx), R22 = 1.0f-2.0f*(qx*qx+qy*qy);
  float L00=R00*sdx, L01=R01*sdy, L02=R02*sdz;
  float L10=R10*sdx, L11=R11*sdy, L12=R12*sdz;
  float L20=R20*sdx, L21=R21*sdy, L22=R22*sdz;
  float a = L00*L00+L01*L01+L02*L02;
  float b = L00*L10+L01*L11+L02*L12;
  float cc= L00*L20+L01*L21+L02*L22;
  float d = L10*L10+L11*L11+L12*L12;
  float e = L10*L20+L11*L21+L12*L22;
  float f = L20*L20+L21*L21+L22*L22;
  float det = a*d*f + 2.0f*e*cc*b - e*e*a - cc*cc*d - b*b*f + 1e-24f;
  float idt = 1.0f/det;
  float ia=(d*f-e*e)*idt, ib=(e*cc-b*f)*idt, ic=(e*b-cc*d)*idt;
  float id=(a*f-cc*cc)*idt, ie=(b*cc-e*a)*idt, iff=(a*d-b*b)*idt;
  posopa[g] = make_float4(xs, ys, zs, opa);
  invrec[2*g+0] = make_float4(-0.5f*ia, -ib, -ic, -0.5f*id);
  invrec[2*g+1] = make_float4(-ie, -0.5f*iff, 0.0f, 0.0f);
}

__global__ __launch_bounds__(512) void gm_evaluate_nobin(
    const float4* __restrict__ posopa, const float4* __restrict__ invrec,
    float* __restrict__ out)
{
  __shared__ int    s_cnt;
  __shared__ float4 s_g[512*3];
  __shared__ float  s_acc[512];
  const int tid = threadIdx.x;
  const int b = blockIdx.x;
  const int bi = cperm(b >> 8), bj = cperm((b >> 4) & 15), bk = cperm(b & 15);
  const float vminx = linf(bi*4) - RELAX, vmaxx = linf(bi*4+3) + RELAX;
  const float vminy = linf(bj*4) - RELAX, vmaxy = linf(bj*4+3) + RELAX;
  const float vminz = linf(bk*4) - RELAX, vmaxz = linf(bk*4+3) + RELAX;
  const int p    = tid & 63;
  const int part = tid >> 6;
  const int sx = p >> 4, sy = (p >> 2) & 3, sz = p & 3;
  const float ptx = linf(bi*4+sx), pty = linf(bj*4+sy), ptz = linf(bk*4+sz);
  float acc = 0.0f;
  for (int c0 = 0; c0 < NG; c0 += 512) {
    if (tid == 0) s_cnt = 0;
    __syncthreads();
    int g = c0 + tid;
    float4 P = posopa[g];
    if (P.w > 0.0f &&
        P.x > vminx && P.x < vmaxx &&
        P.y > vminy && P.y < vmaxy &&
        P.z > vminz && P.z < vmaxz) {
      int slot = atomicAdd(&s_cnt, 1);
      s_g[3*slot+0] = P;
      s_g[3*slot+1] = invrec[2*g+0];
      s_g[3*slot+2] = invrec[2*g+1];
    }
    __syncthreads();
    const int n = s_cnt;
    #pragma unroll 4
    for (int j = part; j < n; j += 8) {
      float4 Pq = s_g[3*j+0];
      float4 I0 = s_g[3*j+1];
      float4 I1 = s_g[3*j+2];
      float px = ptx - Pq.x, py = pty - Pq.y, pz = ptz - Pq.z;
      float power = px*px*I0.x + py*py*I0.w + pz*pz*I1.y
                  + px*py*I0.y + px*pz*I0.z + py*pz*I1.x;
      power = (power > 0.0f) ? -1e10f : power;
      acc += Pq.w * __expf(power);
    }
    __syncthreads();
  }
  s_acc[tid] = acc;
  __syncthreads();
  if (tid < 64) {
    float v = 0.0f;
    #pragma unroll
    for (int w = 0; w < 8; ++w) v += s_acc[tid + w*64];
    out[(bi*4+sx)*4096 + (bj*4+sy)*64 + (bk*4+sz)] = v;
  }
}

extern "C" void kernel_launch(void* const* d_in, const int* in_sizes, int n_in,
                              void* d_out, int out_size, void* d_ws, size_t ws_size,
                              hipStream_t stream) {
  const float* xyz  = (const float*)d_in[0];
  const float* scal = (const float*)d_in[1];
  const float* rot  = (const float*)d_in[2];
  const float* opac = (const float*)d_in[3];
  float* out = (float*)d_out;
  char* ws = (char*)d_ws;
  float4* posopa = (float4*)(ws);                       //  64 KB
  float4* invrec = (float4*)(ws + 65536);               // 128 KB
  int*    bincnt = (int*)(ws + 65536 + 131072);         //  16 KB (4096 bins)
  unsigned short* binidx = (unsigned short*)(ws + 65536 + 131072 + 16384);
  const size_t base = 65536 + 131072 + 16384;

  if (ws_size >= base + (size_t)4096*CAP*2) {
    gm_prep_bin<<<256, 256, 0, stream>>>(xyz, scal, rot, opac,
                                         posopa, invrec, bincnt, binidx);
    gm_evaluate<<<EV_BLOCKS, EV_THREADS, 0, stream>>>(posopa, invrec,
                                         bincnt, binidx, out);
  } else {
    gm_prep<<<8, 512, 0, stream>>>(xyz, scal, rot, opac, posopa, invrec);
    gm_evaluate_nobin<<<4096, 512, 0, stream>>>(posopa, invrec, out);
  }
}

// Round 4
// 156.702 us; speedup vs baseline: 1.1733x; 1.0831x over previous
//
#include <hip/hip_runtime.h>

#define NG 4096
#define RELAX 0.1875f
#define KEEPTH -5.2933049f   // logit(0.005): sigmoid(o)>0.005 <=> o>KEEPTH
#define CHUNK 512
#define EV_THREADS 512
#define EV_BLOCKS 1024
#define EV_ROUNDS 4
#define CAP 2048

__device__ __forceinline__ float linf(int i) { return -1.0f + (2.0f/63.0f)*(float)i; }
// center-first axis permutation: {7,8,6,9,5,10,4,11,3,12,2,13,1,14,0,15}
__device__ __forceinline__ int cperm(int i) { return (i & 1) ? 7 + ((i+1)>>1) : 7 - (i>>1); }

// ======================================================================
// A: fused reduce + transform + 3D binning.  1024 blocks x 256 threads
//    (4 blocks/CU -> 16 waves/CU, vs r3's 1 block/CU).
//  phase 1: redundant masked min/max (identical per block, L2-broadcast)
//  phase 2: transform gaussians [4b, 4b+4) -> packed rec[] (48B/gaussian)
//  phase 3: bin column c=b>>2 over gaussian quarter (b&3); slots via
//           device-scope atomicAdd on globally-zeroed bincnt
// ======================================================================
__global__ __launch_bounds__(256) void gm_prep_bin(
    const float* __restrict__ xyz, const float* __restrict__ scal,
    const float* __restrict__ rot, const float* __restrict__ opac,
    float4* __restrict__ rec,
    int* __restrict__ bincnt, unsigned short* __restrict__ binidx)
{
  __shared__ float s_r[4][6];
  const int tid = threadIdx.x;
  const int b   = blockIdx.x;            // 0..1023
  const float4* xyz4 = (const float4*)xyz;
  const float4* op4  = (const float4*)opac;

  // ---- phase 1: masked min/max (exp-free, vectorized, redundant) ----
  float mn0=1e10f, mn1=1e10f, mn2=1e10f;
  float mx0=-1e10f, mx1=-1e10f, mx2=-1e10f;
  #pragma unroll
  for (int t = 0; t < 4; ++t) {
    const int G = t*256 + tid;           // group of 4 gaussians
    float4 v0 = xyz4[3*G+0], v1 = xyz4[3*G+1], v2 = xyz4[3*G+2];
    float4 oo = op4[G];
    if (oo.x > KEEPTH) { mn0=fminf(mn0,v0.x); mx0=fmaxf(mx0,v0.x);
                         mn1=fminf(mn1,v0.y); mx1=fmaxf(mx1,v0.y);
                         mn2=fminf(mn2,v0.z); mx2=fmaxf(mx2,v0.z); }
    if (oo.y > KEEPTH) { mn0=fminf(mn0,v0.w); mx0=fmaxf(mx0,v0.w);
                         mn1=fminf(mn1,v1.x); mx1=fmaxf(mx1,v1.x);
                         mn2=fminf(mn2,v1.y); mx2=fmaxf(mx2,v1.y); }
    if (oo.z > KEEPTH) { mn0=fminf(mn0,v1.z); mx0=fmaxf(mx0,v1.z);
                         mn1=fminf(mn1,v1.w); mx1=fmaxf(mx1,v1.w);
                         mn2=fminf(mn2,v2.x); mx2=fmaxf(mx2,v2.x); }
    if (oo.w > KEEPTH) { mn0=fminf(mn0,v2.y); mx0=fmaxf(mx0,v2.y);
                         mn1=fminf(mn1,v2.z); mx1=fmaxf(mx1,v2.z);
                         mn2=fminf(mn2,v2.w); mx2=fmaxf(mx2,v2.w); }
  }
  #pragma unroll
  for (int s = 1; s < 64; s <<= 1) {
    mn0 = fminf(mn0, __shfl_xor(mn0, s)); mx0 = fmaxf(mx0, __shfl_xor(mx0, s));
    mn1 = fminf(mn1, __shfl_xor(mn1, s)); mx1 = fmaxf(mx1, __shfl_xor(mx1, s));
    mn2 = fminf(mn2, __shfl_xor(mn2, s)); mx2 = fmaxf(mx2, __shfl_xor(mx2, s));
  }
  if ((tid & 63) == 0) {
    const int w = tid >> 6;
    s_r[w][0]=mn0; s_r[w][1]=mn1; s_r[w][2]=mn2;
    s_r[w][3]=mx0; s_r[w][4]=mx1; s_r[w][5]=mx2;
  }
  __syncthreads();
  mn0 = fminf(fminf(s_r[0][0],s_r[1][0]), fminf(s_r[2][0],s_r[3][0]));
  mn1 = fminf(fminf(s_r[0][1],s_r[1][1]), fminf(s_r[2][1],s_r[3][1]));
  mn2 = fminf(fminf(s_r[0][2],s_r[1][2]), fminf(s_r[2][2],s_r[3][2]));
  mx0 = fmaxf(fmaxf(s_r[0][3],s_r[1][3]), fmaxf(s_r[2][3],s_r[3][3]));
  mx1 = fmaxf(fmaxf(s_r[0][4],s_r[1][4]), fmaxf(s_r[2][4],s_r[3][4]));
  mx2 = fmaxf(fmaxf(s_r[0][5],s_r[1][5]), fmaxf(s_r[2][5],s_r[3][5]));
  const float cx = (mn0+mx0)*0.5f;
  const float cy = (mn1+mx1)*0.5f;
  const float cz = (mn2+mx2)*0.5f;
  const float sc = 1.8f/fmaxf(mx0-mn0, fmaxf(mx1-mn1, mx2-mn2));

  // ---- phase 2: transform my 4 gaussians -> packed rec ----
  if (tid < 4) {
    const int g = b*4 + tid;
    float o = opac[g];
    float sig = 1.0f/(1.0f + __expf(-o));
    float opa = (sig > 0.005f) ? sig : 0.0f;
    float xs = (xyz[3*g+0]-cx)*sc;
    float ys = (xyz[3*g+1]-cy)*sc;
    float zs = (xyz[3*g+2]-cz)*sc;
    float sdx = __expf(scal[3*g+0])*sc;
    float sdy = __expf(scal[3*g+1])*sc;
    float sdz = __expf(scal[3*g+2])*sc;
    float qr=rot[4*g+0], qx=rot[4*g+1], qy=rot[4*g+2], qz=rot[4*g+3];
    float qn = 1.0f/sqrtf(qr*qr+qx*qx+qy*qy+qz*qz);
    qr*=qn; qx*=qn; qy*=qn; qz*=qn;
    float R00 = 1.0f-2.0f*(qy*qy+qz*qz), R01 = 2.0f*(qx*qy-qr*qz), R02 = 2.0f*(qx*qz+qr*qy);
    float R10 = 2.0f*(qx*qy+qr*qz), R11 = 1.0f-2.0f*(qx*qx+qz*qz), R12 = 2.0f*(qy*qz-qr*qx);
    float R20 = 2.0f*(qx*qz-qr*qy), R21 = 2.0f*(qy*qz+qr*qx), R22 = 1.0f-2.0f*(qx*qx+qy*qy);
    float L00=R00*sdx, L01=R01*sdy, L02=R02*sdz;
    float L10=R10*sdx, L11=R11*sdy, L12=R12*sdz;
    float L20=R20*sdx, L21=R21*sdy, L22=R22*sdz;
    float a = L00*L00+L01*L01+L02*L02;
    float bb= L00*L10+L01*L11+L02*L12;
    float cc= L00*L20+L01*L21+L02*L22;
    float d = L10*L10+L11*L11+L12*L12;
    float e = L10*L20+L11*L21+L12*L22;
    float f = L20*L20+L21*L21+L22*L22;
    float det = a*d*f + 2.0f*e*cc*bb - e*e*a - cc*cc*d - bb*bb*f + 1e-24f;
    float idt = 1.0f/det;
    float ia=(d*f-e*e)*idt, ib=(e*cc-bb*f)*idt, ic=(e*bb-cc*d)*idt;
    float id=(a*f-cc*cc)*idt, ie=(bb*cc-e*a)*idt, iff=(a*d-bb*bb)*idt;
    rec[3*g+0] = make_float4(xs, ys, zs, opa);
    rec[3*g+1] = make_float4(-0.5f*ia, -ib, -ic, -0.5f*id);
    rec[3*g+2] = make_float4(-ie, -0.5f*iff, 0.0f, 0.0f);
  }

  // ---- phase 3: bin column c=b>>2 over quarter (b&3) ----
  const int c  = b >> 2;                 // 0..255 = bi*16+bj
  const int bi = c >> 4, bj = c & 15;
  const float vminx = linf(bi*4) - RELAX, vmaxx = linf(bi*4+3) + RELAX;
  const float vminy = linf(bj*4) - RELAX, vmaxy = linf(bj*4+3) + RELAX;
  {
    const int G = (b & 3)*256 + tid;     // my float4-group of 4 gaussians
    float4 v0 = xyz4[3*G+0], v1 = xyz4[3*G+1], v2 = xyz4[3*G+2];
    float4 oo = op4[G];
    float gx[4] = {v0.x, v0.w, v1.z, v2.y};
    float gy[4] = {v0.y, v1.x, v1.w, v2.z};
    float gz[4] = {v0.z, v1.y, v2.x, v2.w};
    float go[4] = {oo.x, oo.y, oo.z, oo.w};
    #pragma unroll
    for (int u = 0; u < 4; ++u) {
      if (!(go[u] > KEEPTH)) continue;
      float xs = (gx[u]-cx)*sc;          // same exprs as phase 2
      float ys = (gy[u]-cy)*sc;
      float zs = (gz[u]-cz)*sc;
      if (xs > vminx && xs < vmaxx && ys > vminy && ys < vmaxy) {
        int klo = (int)floorf(((zs + 0.8125f)*31.5f - 3.0f)*0.25f) - 1;
        int khi = (int)floorf((zs + 1.1875f)*7.875f) + 1;
        klo = max(klo, 0); khi = min(khi, 15);
        for (int bk = klo; bk <= khi; ++bk) {
          float lo = linf(bk*4) - RELAX, hi = linf(bk*4+3) + RELAX;
          if (zs > lo && zs < hi) {
            int slot = atomicAdd(&bincnt[(c<<4) + bk], 1);  // device-scope
            if (slot < CAP)
              binidx[(size_t)((c<<4) + bk)*CAP + slot] = (unsigned short)(4*G+u);
          }
        }
      }
    }
  }
}

// ======================================================================
// B: eval.  1024 blocks x 512 thr (4 blocks/CU = full 32-wave residency),
// 4 bins per block, column decorrelated per round:
//   q = k*1024 + ((bid + k*331) & 1023)
// -> each block's 4 bins sit in qi-strata {0-3},{4-7},{8-11},{12-15}
//    (graded bi-centrality) with shifted (bj,bk) -> <=1 heavy bin/block.
// ======================================================================
__global__ __launch_bounds__(EV_THREADS) void gm_evaluate(
    const float4* __restrict__ rec,
    const int* __restrict__ bincnt, const unsigned short* __restrict__ binidx,
    float* __restrict__ out)
{
  __shared__ float4 s_g[CHUNK*3];       // 24 KB
  __shared__ float  s_acc[EV_THREADS];  //  2 KB
  const int tid  = threadIdx.x;
  const int p    = tid & 63;
  const int part = tid >> 6;            // 0..7
  const int sx = p >> 4, sy = (p >> 2) & 3, sz = p & 3;

  for (int k = 0; k < EV_ROUNDS; ++k) {
    const int q  = k*EV_BLOCKS + ((blockIdx.x + k*331) & (EV_BLOCKS-1));
    const int bi = cperm(q >> 8), bj = cperm((q >> 4) & 15), bk = cperm(q & 15);
    const int bin = (bi*16 + bj)*16 + bk;
    const int n = min(bincnt[bin], CAP);
    const int obase = (bi*4+sx)*4096 + (bj*4+sy)*64 + (bk*4+sz);

    if (n == 0) {                       // block-uniform: no barriers needed
      if (tid < 64) out[obase] = 0.0f;
      continue;
    }

    const float ptx = linf(bi*4+sx), pty = linf(bj*4+sy), ptz = linf(bk*4+sz);
    const unsigned short* mylist = binidx + (size_t)bin*CAP;
    float acc = 0.0f;

    for (int c0 = 0; c0 < n; c0 += CHUNK) {
      __syncthreads();                  // s_g safe to overwrite
      const int lim = min(n - c0, CHUNK);
      if (tid < lim) {                  // EV_THREADS == CHUNK
        int g = mylist[c0 + tid];
        s_g[3*tid+0] = rec[3*g+0];
        s_g[3*tid+1] = rec[3*g+1];
        s_g[3*tid+2] = rec[3*g+2];
      }
      __syncthreads();
      #pragma unroll 4
      for (int j = part; j < lim; j += 8) {
        float4 P  = s_g[3*j+0];
        float4 I0 = s_g[3*j+1];
        float4 I1 = s_g[3*j+2];
        float px = ptx - P.x, py = pty - P.y, pz = ptz - P.z;
        float power = px*px*I0.x + py*py*I0.w + pz*pz*I1.y
                    + px*py*I0.y + px*pz*I0.z + py*pz*I1.x;
        power = (power > 0.0f) ? -1e10f : power;   // branchless
        acc += P.w * __expf(power);
      }
    }

    __syncthreads();                    // prev readers of s_acc done
    s_acc[tid] = acc;
    __syncthreads();
    if (tid < 64) {
      float v = 0.0f;
      #pragma unroll
      for (int w = 0; w < 8; ++w) v += s_acc[tid + w*64];
      out[obase] = v;
    }
  }
}

// ======================================================================
// Fallback path (ws too small for 3D bins): prep + brute-force eval
// ======================================================================
__global__ __launch_bounds__(512) void gm_prep(
    const float* __restrict__ xyz, const float* __restrict__ scal,
    const float* __restrict__ rot, const float* __restrict__ opac,
    float4* __restrict__ rec)
{
  __shared__ float s_mn[3][512];
  __shared__ float s_mx[3][512];
  const int tid = threadIdx.x;
  float mn0=1e10f, mn1=1e10f, mn2=1e10f;
  float mx0=-1e10f, mx1=-1e10f, mx2=-1e10f;
  #pragma unroll
  for (int t = 0; t < NG/512; ++t) {
    int g = t*512 + tid;
    float o = opac[g];
    bool keep = o > KEEPTH;
    float x = xyz[3*g+0], y = xyz[3*g+1], z = xyz[3*g+2];
    if (keep) {
      mn0 = fminf(mn0, x); mn1 = fminf(mn1, y); mn2 = fminf(mn2, z);
      mx0 = fmaxf(mx0, x); mx1 = fmaxf(mx1, y); mx2 = fmaxf(mx2, z);
    }
  }
  s_mn[0][tid]=mn0; s_mn[1][tid]=mn1; s_mn[2][tid]=mn2;
  s_mx[0][tid]=mx0; s_mx[1][tid]=mx1; s_mx[2][tid]=mx2;
  __syncthreads();
  for (int s = 256; s > 0; s >>= 1) {
    if (tid < s) {
      #pragma unroll
      for (int k = 0; k < 3; ++k) {
        s_mn[k][tid] = fminf(s_mn[k][tid], s_mn[k][tid+s]);
        s_mx[k][tid] = fmaxf(s_mx[k][tid], s_mx[k][tid+s]);
      }
    }
    __syncthreads();
  }
  const float cx = (s_mn[0][0]+s_mx[0][0])*0.5f;
  const float cy = (s_mn[1][0]+s_mx[1][0])*0.5f;
  const float cz = (s_mn[2][0]+s_mx[2][0])*0.5f;
  const float rmax = fmaxf(s_mx[0][0]-s_mn[0][0],
                     fmaxf(s_mx[1][0]-s_mn[1][0], s_mx[2][0]-s_mn[2][0]));
  const float sc = 1.8f/rmax;

  const int g = blockIdx.x*512 + tid;
  float o = opac[g];
  float sig = 1.0f/(1.0f + __expf(-o));
  float opa = (sig > 0.005f) ? sig : 0.0f;
  float xs = (xyz[3*g+0]-cx)*sc;
  float ys = (xyz[3*g+1]-cy)*sc;
  float zs = (xyz[3*g+2]-cz)*sc;
  float sdx = __expf(scal[3*g+0])*sc;
  float sdy = __expf(scal[3*g+1])*sc;
  float sdz = __expf(scal[3*g+2])*sc;
  float qr=rot[4*g+0], qx=rot[4*g+1], qy=rot[4*g+2], qz=rot[4*g+3];
  float qn = 1.0f/sqrtf(qr*qr+qx*qx+qy*qy+qz*qz);
  qr*=qn; qx*=qn; qy*=qn; qz*=qn;
  float R00 = 1.0f-2.0f*(qy*qy+qz*qz), R01 = 2.0f*(qx*qy-qr*qz), R02 = 2.0f*(qx*qz+qr*qy);
  float R10 = 2.0f*(qx*qy+qr*qz), R11 = 1.0f-2.0f*(qx*qx+qz*qz), R12 = 2.0f*(qy*qz-qr*qx);
  float R20 = 2.0f*(qx*qz-qr*qy), R21 = 2.0f*(qy*qz+qr*qx), R22 = 1.0f-2.0f*(qx*qx+qy*qy);
  float L00=R00*sdx, L01=R01*sdy, L02=R02*sdz;
  float L10=R10*sdx, L11=R11*sdy, L12=R12*sdz;
  float L20=R20*sdx, L21=R21*sdy, L22=R22*sdz;
  float a = L00*L00+L01*L01+L02*L02;
  float b = L00*L10+L01*L11+L02*L12;
  float cc= L00*L20+L01*L21+L02*L22;
  float d = L10*L10+L11*L11+L12*L12;
  float e = L10*L20+L11*L21+L12*L22;
  float f = L20*L20+L21*L21+L22*L22;
  float det = a*d*f + 2.0f*e*cc*b - e*e*a - cc*cc*d - b*b*f + 1e-24f;
  float idt = 1.0f/det;
  float ia=(d*f-e*e)*idt, ib=(e*cc-b*f)*idt, ic=(e*b-cc*d)*idt;
  float id=(a*f-cc*cc)*idt, ie=(b*cc-e*a)*idt, iff=(a*d-b*b)*idt;
  rec[3*g+0] = make_float4(xs, ys, zs, opa);
  rec[3*g+1] = make_float4(-0.5f*ia, -ib, -ic, -0.5f*id);
  rec[3*g+2] = make_float4(-ie, -0.5f*iff, 0.0f, 0.0f);
}

__global__ __launch_bounds__(512) void gm_evaluate_nobin(
    const float4* __restrict__ rec, float* __restrict__ out)
{
  __shared__ int    s_cnt;
  __shared__ float4 s_g[512*3];
  __shared__ float  s_acc[512];
  const int tid = threadIdx.x;
  const int b = blockIdx.x;
  const int bi = cperm(b >> 8), bj = cperm((b >> 4) & 15), bk = cperm(b & 15);
  const float vminx = linf(bi*4) - RELAX, vmaxx = linf(bi*4+3) + RELAX;
  const float vminy = linf(bj*4) - RELAX, vmaxy = linf(bj*4+3) + RELAX;
  const float vminz = linf(bk*4) - RELAX, vmaxz = linf(bk*4+3) + RELAX;
  const int p    = tid & 63;
  const int part = tid >> 6;
  const int sx = p >> 4, sy = (p >> 2) & 3, sz = p & 3;
  const float ptx = linf(bi*4+sx), pty = linf(bj*4+sy), ptz = linf(bk*4+sz);
  float acc = 0.0f;
  for (int c0 = 0; c0 < NG; c0 += 512) {
    if (tid == 0) s_cnt = 0;
    __syncthreads();
    int g = c0 + tid;
    float4 P = rec[3*g+0];
    if (P.w > 0.0f &&
        P.x > vminx && P.x < vmaxx &&
        P.y > vminy && P.y < vmaxy &&
        P.z > vminz && P.z < vmaxz) {
      int slot = atomicAdd(&s_cnt, 1);
      s_g[3*slot+0] = P;
      s_g[3*slot+1] = rec[3*g+1];
      s_g[3*slot+2] = rec[3*g+2];
    }
    __syncthreads();
    const int n = s_cnt;
    #pragma unroll 4
    for (int j = part; j < n; j += 8) {
      float4 Pq = s_g[3*j+0];
      float4 I0 = s_g[3*j+1];
      float4 I1 = s_g[3*j+2];
      float px = ptx - Pq.x, py = pty - Pq.y, pz = ptz - Pq.z;
      float power = px*px*I0.x + py*py*I0.w + pz*pz*I1.y
                  + px*py*I0.y + px*pz*I0.z + py*pz*I1.x;
      power = (power > 0.0f) ? -1e10f : power;
      acc += Pq.w * __expf(power);
    }
    __syncthreads();
  }
  s_acc[tid] = acc;
  __syncthreads();
  if (tid < 64) {
    float v = 0.0f;
    #pragma unroll
    for (int w = 0; w < 8; ++w) v += s_acc[tid + w*64];
    out[(bi*4+sx)*4096 + (bj*4+sy)*64 + (bk*4+sz)] = v;
  }
}

extern "C" void kernel_launch(void* const* d_in, const int* in_sizes, int n_in,
                              void* d_out, int out_size, void* d_ws, size_t ws_size,
                              hipStream_t stream) {
  const float* xyz  = (const float*)d_in[0];
  const float* scal = (const float*)d_in[1];
  const float* rot  = (const float*)d_in[2];
  const float* opac = (const float*)d_in[3];
  float* out = (float*)d_out;
  char* ws = (char*)d_ws;
  float4* rec    = (float4*)ws;                          // 192 KB (P,I0,I1)x4096
  int*    bincnt = (int*)(ws + 196608);                  //  16 KB (4096 bins)
  unsigned short* binidx = (unsigned short*)(ws + 196608 + 16384);
  const size_t base = 196608 + 16384;

  if (ws_size >= base + (size_t)4096*CAP*2) {
    hipMemsetAsync(bincnt, 0, 4096*sizeof(int), stream);  // graph-capturable
    gm_prep_bin<<<1024, 256, 0, stream>>>(xyz, scal, rot, opac,
                                          rec, bincnt, binidx);
    gm_evaluate<<<EV_BLOCKS, EV_THREADS, 0, stream>>>(rec, bincnt, binidx, out);
  } else {
    gm_prep<<<8, 512, 0, stream>>>(xyz, scal, rot, opac, rec);
    gm_evaluate_nobin<<<4096, 512, 0, stream>>>(rec, out);
  }
}

// Round 5
// 98.770 us; speedup vs baseline: 1.8615x; 1.5865x over previous
//
#include <hip/hip_runtime.h>

#define NG 4096
#define RELAX 0.1875f
#define KEEPTH -5.2933049f   // logit(0.005): sigmoid(o)>0.005 <=> o>KEEPTH
#define SLICES 8
#define SLICE_G (NG/SLICES)  // 512 gaussians per slice
#define EV_THREADS 256

__device__ __forceinline__ float linf(int i) { return -1.0f + (2.0f/63.0f)*(float)i; }

// ======================================================================
// A: prep.  16 blocks x 256 threads.
//  - redundant masked min/max (identical, deterministic in every block)
//  - transform 1 gaussian/thread -> posopa (scan array) + invrec (gather)
//  - zero the output buffer (so eval can atomicAdd partials)
// ======================================================================
__global__ __launch_bounds__(256) void gm_prep(
    const float* __restrict__ xyz, const float* __restrict__ scal,
    const float* __restrict__ rot, const float* __restrict__ opac,
    float4* __restrict__ posopa, float4* __restrict__ invrec,
    float4* __restrict__ out4)
{
  __shared__ float s_r[4][6];
  const int tid = threadIdx.x;
  const int b   = blockIdx.x;            // 0..15
  const float4* xyz4 = (const float4*)xyz;
  const float4* op4  = (const float4*)opac;

  // ---- zero out: 16 blk x 256 thr x 16 float4 = 1 MB ----
  {
    const int t0 = b*256 + tid;
    #pragma unroll
    for (int i = 0; i < 16; ++i) out4[t0 + i*4096] = make_float4(0,0,0,0);
  }

  // ---- redundant masked min/max (exp-free, vectorized) ----
  float mn0=1e10f, mn1=1e10f, mn2=1e10f;
  float mx0=-1e10f, mx1=-1e10f, mx2=-1e10f;
  #pragma unroll
  for (int t = 0; t < 4; ++t) {
    const int G = t*256 + tid;           // group of 4 gaussians
    float4 v0 = xyz4[3*G+0], v1 = xyz4[3*G+1], v2 = xyz4[3*G+2];
    float4 oo = op4[G];
    if (oo.x > KEEPTH) { mn0=fminf(mn0,v0.x); mx0=fmaxf(mx0,v0.x);
                         mn1=fminf(mn1,v0.y); mx1=fmaxf(mx1,v0.y);
                         mn2=fminf(mn2,v0.z); mx2=fmaxf(mx2,v0.z); }
    if (oo.y > KEEPTH) { mn0=fminf(mn0,v0.w); mx0=fmaxf(mx0,v0.w);
                         mn1=fminf(mn1,v1.x); mx1=fmaxf(mx1,v1.x);
                         mn2=fminf(mn2,v1.y); mx2=fmaxf(mx2,v1.y); }
    if (oo.z > KEEPTH) { mn0=fminf(mn0,v1.z); mx0=fmaxf(mx0,v1.z);
                         mn1=fminf(mn1,v1.w); mx1=fmaxf(mx1,v1.w);
                         mn2=fminf(mn2,v2.x); mx2=fmaxf(mx2,v2.x); }
    if (oo.w > KEEPTH) { mn0=fminf(mn0,v2.y); mx0=fmaxf(mx0,v2.y);
                         mn1=fminf(mn1,v2.z); mx1=fmaxf(mx1,v2.z);
                         mn2=fminf(mn2,v2.w); mx2=fmaxf(mx2,v2.w); }
  }
  #pragma unroll
  for (int s = 1; s < 64; s <<= 1) {
    mn0 = fminf(mn0, __shfl_xor(mn0, s)); mx0 = fmaxf(mx0, __shfl_xor(mx0, s));
    mn1 = fminf(mn1, __shfl_xor(mn1, s)); mx1 = fmaxf(mx1, __shfl_xor(mx1, s));
    mn2 = fminf(mn2, __shfl_xor(mn2, s)); mx2 = fmaxf(mx2, __shfl_xor(mx2, s));
  }
  if ((tid & 63) == 0) {
    const int w = tid >> 6;
    s_r[w][0]=mn0; s_r[w][1]=mn1; s_r[w][2]=mn2;
    s_r[w][3]=mx0; s_r[w][4]=mx1; s_r[w][5]=mx2;
  }
  __syncthreads();
  mn0 = fminf(fminf(s_r[0][0],s_r[1][0]), fminf(s_r[2][0],s_r[3][0]));
  mn1 = fminf(fminf(s_r[0][1],s_r[1][1]), fminf(s_r[2][1],s_r[3][1]));
  mn2 = fminf(fminf(s_r[0][2],s_r[1][2]), fminf(s_r[2][2],s_r[3][2]));
  mx0 = fmaxf(fmaxf(s_r[0][3],s_r[1][3]), fmaxf(s_r[2][3],s_r[3][3]));
  mx1 = fmaxf(fmaxf(s_r[0][4],s_r[1][4]), fmaxf(s_r[2][4],s_r[3][4]));
  mx2 = fmaxf(fmaxf(s_r[0][5],s_r[1][5]), fmaxf(s_r[2][5],s_r[3][5]));
  const float cx = (mn0+mx0)*0.5f;
  const float cy = (mn1+mx1)*0.5f;
  const float cz = (mn2+mx2)*0.5f;
  const float sc = 1.8f/fmaxf(mx0-mn0, fmaxf(mx1-mn1, mx2-mn2));

  // ---- transform my gaussian ----
  const int g = b*256 + tid;
  float o = opac[g];
  float sig = 1.0f/(1.0f + __expf(-o));
  float opa = (sig > 0.005f) ? sig : 0.0f;
  float xs = (xyz[3*g+0]-cx)*sc;
  float ys = (xyz[3*g+1]-cy)*sc;
  float zs = (xyz[3*g+2]-cz)*sc;
  float sdx = __expf(scal[3*g+0])*sc;
  float sdy = __expf(scal[3*g+1])*sc;
  float sdz = __expf(scal[3*g+2])*sc;
  float qr=rot[4*g+0], qx=rot[4*g+1], qy=rot[4*g+2], qz=rot[4*g+3];
  float qn = 1.0f/sqrtf(qr*qr+qx*qx+qy*qy+qz*qz);
  qr*=qn; qx*=qn; qy*=qn; qz*=qn;
  float R00 = 1.0f-2.0f*(qy*qy+qz*qz), R01 = 2.0f*(qx*qy-qr*qz), R02 = 2.0f*(qx*qz+qr*qy);
  float R10 = 2.0f*(qx*qy+qr*qz), R11 = 1.0f-2.0f*(qx*qx+qz*qz), R12 = 2.0f*(qy*qz-qr*qx);
  float R20 = 2.0f*(qx*qz-qr*qy), R21 = 2.0f*(qy*qz+qr*qx), R22 = 1.0f-2.0f*(qx*qx+qy*qy);
  float L00=R00*sdx, L01=R01*sdy, L02=R02*sdz;
  float L10=R10*sdx, L11=R11*sdy, L12=R12*sdz;
  float L20=R20*sdx, L21=R21*sdy, L22=R22*sdz;
  float a = L00*L00+L01*L01+L02*L02;
  float bb= L00*L10+L01*L11+L02*L12;
  float cc= L00*L20+L01*L21+L02*L22;
  float d = L10*L10+L11*L11+L12*L12;
  float e = L10*L20+L11*L21+L12*L22;
  float f = L20*L20+L21*L21+L22*L22;
  float det = a*d*f + 2.0f*e*cc*bb - e*e*a - cc*cc*d - bb*bb*f + 1e-24f;
  float idt = 1.0f/det;
  float ia=(d*f-e*e)*idt, ib=(e*cc-bb*f)*idt, ic=(e*bb-cc*d)*idt;
  float id=(a*f-cc*cc)*idt, ie=(bb*cc-e*a)*idt, iff=(a*d-bb*bb)*idt;
  posopa[g]     = make_float4(xs, ys, zs, opa);
  invrec[2*g+0] = make_float4(-0.5f*ia, -ib, -ic, -0.5f*id);
  invrec[2*g+1] = make_float4(-ie, -0.5f*iff, 0.0f, 0.0f);
}

// ======================================================================
// B: eval.  grid = 4096 bins x 8 slices = 32768 blocks x 256 threads.
// Block (bin, s): scan gaussians [s*512, s*512+512) of posopa with the
// exact window test, compact survivors (<=512, provably) into LDS,
// evaluate 64 voxels, atomicAdd one partial per voxel.
// Work quantum <= ~160 records -> ~1 us max block; no bin lists; no
// contended counters; tail and launch overhead both collapse.
// ======================================================================
__global__ __launch_bounds__(EV_THREADS) void gm_eval(
    const float4* __restrict__ posopa, const float4* __restrict__ invrec,
    float* __restrict__ out)
{
  __shared__ float4 s_g[SLICE_G*3];     // 24 KB (512 records max)
  __shared__ float  s_acc[EV_THREADS];  //  1 KB
  __shared__ int    s_cnt;
  const int tid  = threadIdx.x;
  const int bin  = blockIdx.x >> 3;
  const int sl   = blockIdx.x & 7;
  const int bi = bin >> 8, bj = (bin >> 4) & 15, bk = bin & 15;
  const float vminx = linf(bi*4) - RELAX, vmaxx = linf(bi*4+3) + RELAX;
  const float vminy = linf(bj*4) - RELAX, vmaxy = linf(bj*4+3) + RELAX;
  const float vminz = linf(bk*4) - RELAX, vmaxz = linf(bk*4+3) + RELAX;
  if (tid == 0) s_cnt = 0;
  __syncthreads();

  // ---- scan my 512-gaussian slice, compact survivors ----
  #pragma unroll
  for (int t = 0; t < SLICE_G/EV_THREADS; ++t) {
    const int g = sl*SLICE_G + t*EV_THREADS + tid;
    float4 P = posopa[g];
    if (P.w > 0.0f &&
        P.x > vminx && P.x < vmaxx &&
        P.y > vminy && P.y < vmaxy &&
        P.z > vminz && P.z < vmaxz) {
      int slot = atomicAdd(&s_cnt, 1);
      s_g[3*slot+0] = P;
      s_g[3*slot+1] = invrec[2*g+0];
      s_g[3*slot+2] = invrec[2*g+1];
    }
  }
  __syncthreads();
  const int n = s_cnt;
  if (n == 0) return;                   // out pre-zeroed by prep

  // ---- evaluate 64 voxels x n records (4 waves split records) ----
  const int p    = tid & 63;
  const int part = tid >> 6;            // 0..3
  const int sx = p >> 4, sy = (p >> 2) & 3, sz = p & 3;
  const float ptx = linf(bi*4+sx), pty = linf(bj*4+sy), ptz = linf(bk*4+sz);
  float acc = 0.0f;
  #pragma unroll 4
  for (int j = part; j < n; j += 4) {
    float4 P  = s_g[3*j+0];
    float4 I0 = s_g[3*j+1];
    float4 I1 = s_g[3*j+2];
    float px = ptx - P.x, py = pty - P.y, pz = ptz - P.z;
    float power = px*px*I0.x + py*py*I0.w + pz*pz*I1.y
                + px*py*I0.y + px*pz*I0.z + py*pz*I1.x;
    power = (power > 0.0f) ? -1e10f : power;   // branchless
    acc += P.w * __expf(power);
  }
  s_acc[tid] = acc;
  __syncthreads();
  if (tid < 64) {
    float v = s_acc[tid] + s_acc[tid+64] + s_acc[tid+128] + s_acc[tid+192];
    atomicAdd(&out[(bi*4+sx)*4096 + (bj*4+sy)*64 + (bk*4+sz)], v);
  }
}

// ======================================================================
// Fallback (ws too small even for 192 KB): fully fused, zero-workspace,
// correct for any input; each block redundantly computes everything.
// ======================================================================
__global__ __launch_bounds__(256) void gm_fused_nows(
    const float* __restrict__ xyz, const float* __restrict__ scal,
    const float* __restrict__ rot, const float* __restrict__ opac,
    float* __restrict__ out)
{
  __shared__ float s_r[4][6];
  __shared__ float4 s_g[256*3];
  __shared__ float  s_acc[256];
  __shared__ int    s_cnt;
  const int tid = threadIdx.x;
  const float4* xyz4 = (const float4*)xyz;
  const float4* op4  = (const float4*)opac;

  float mn0=1e10f, mn1=1e10f, mn2=1e10f;
  float mx0=-1e10f, mx1=-1e10f, mx2=-1e10f;
  #pragma unroll
  for (int t = 0; t < 4; ++t) {
    const int G = t*256 + tid;
    float4 v0 = xyz4[3*G+0], v1 = xyz4[3*G+1], v2 = xyz4[3*G+2];
    float4 oo = op4[G];
    if (oo.x > KEEPTH) { mn0=fminf(mn0,v0.x); mx0=fmaxf(mx0,v0.x);
                         mn1=fminf(mn1,v0.y); mx1=fmaxf(mx1,v0.y);
                         mn2=fminf(mn2,v0.z); mx2=fmaxf(mx2,v0.z); }
    if (oo.y > KEEPTH) { mn0=fminf(mn0,v0.w); mx0=fmaxf(mx0,v0.w);
                         mn1=fminf(mn1,v1.x); mx1=fmaxf(mx1,v1.x);
                         mn2=fminf(mn2,v1.y); mx2=fmaxf(mx2,v1.y); }
    if (oo.z > KEEPTH) { mn0=fminf(mn0,v1.z); mx0=fmaxf(mx0,v1.z);
                         mn1=fminf(mn1,v1.w); mx1=fmaxf(mx1,v1.w);
                         mn2=fminf(mn2,v2.x); mx2=fmaxf(mx2,v2.x); }
    if (oo.w > KEEPTH) { mn0=fminf(mn0,v2.y); mx0=fmaxf(mx0,v2.y);
                         mn1=fminf(mn1,v2.z); mx1=fmaxf(mx1,v2.z);
                         mn2=fminf(mn2,v2.w); mx2=fmaxf(mx2,v2.w); }
  }
  #pragma unroll
  for (int s = 1; s < 64; s <<= 1) {
    mn0 = fminf(mn0, __shfl_xor(mn0, s)); mx0 = fmaxf(mx0, __shfl_xor(mx0, s));
    mn1 = fminf(mn1, __shfl_xor(mn1, s)); mx1 = fmaxf(mx1, __shfl_xor(mx1, s));
    mn2 = fminf(mn2, __shfl_xor(mn2, s)); mx2 = fmaxf(mx2, __shfl_xor(mx2, s));
  }
  if ((tid & 63) == 0) {
    const int w = tid >> 6;
    s_r[w][0]=mn0; s_r[w][1]=mn1; s_r[w][2]=mn2;
    s_r[w][3]=mx0; s_r[w][4]=mx1; s_r[w][5]=mx2;
  }
  if (tid == 0) s_cnt = 0;
  __syncthreads();
  mn0 = fminf(fminf(s_r[0][0],s_r[1][0]), fminf(s_r[2][0],s_r[3][0]));
  mn1 = fminf(fminf(s_r[0][1],s_r[1][1]), fminf(s_r[2][1],s_r[3][1]));
  mn2 = fminf(fminf(s_r[0][2],s_r[1][2]), fminf(s_r[2][2],s_r[3][2]));
  mx0 = fmaxf(fmaxf(s_r[0][3],s_r[1][3]), fmaxf(s_r[2][3],s_r[3][3]));
  mx1 = fmaxf(fmaxf(s_r[0][4],s_r[1][4]), fmaxf(s_r[2][4],s_r[3][4]));
  mx2 = fmaxf(fmaxf(s_r[0][5],s_r[1][5]), fmaxf(s_r[2][5],s_r[3][5]));
  const float cx = (mn0+mx0)*0.5f;
  const float cy = (mn1+mx1)*0.5f;
  const float cz = (mn2+mx2)*0.5f;
  const float sc = 1.8f/fmaxf(mx0-mn0, fmaxf(mx1-mn1, mx2-mn2));

  const int bin = blockIdx.x;
  const int bi = bin >> 8, bj = (bin >> 4) & 15, bk = bin & 15;
  const float vminx = linf(bi*4) - RELAX, vmaxx = linf(bi*4+3) + RELAX;
  const float vminy = linf(bj*4) - RELAX, vmaxy = linf(bj*4+3) + RELAX;
  const float vminz = linf(bk*4) - RELAX, vmaxz = linf(bk*4+3) + RELAX;
  const int p    = tid & 63;
  const int part = tid >> 6;
  const int sx = p >> 4, sy = (p >> 2) & 3, sz = p & 3;
  const float ptx = linf(bi*4+sx), pty = linf(bj*4+sy), ptz = linf(bk*4+sz);
  float acc = 0.0f;

  for (int c0 = 0; c0 < NG; c0 += 256) {
    const int g = c0 + tid;
    float o = opac[g];
    bool pass = false;
    float xs=0, ys=0, zs=0, sig=0;
    if (o > KEEPTH) {
      sig = 1.0f/(1.0f + __expf(-o));
      xs = (xyz[3*g+0]-cx)*sc;
      ys = (xyz[3*g+1]-cy)*sc;
      zs = (xyz[3*g+2]-cz)*sc;
      pass = xs > vminx && xs < vmaxx &&
             ys > vminy && ys < vmaxy &&
             zs > vminz && zs < vmaxz;
    }
    if (pass) {
      float sdx = __expf(scal[3*g+0])*sc;
      float sdy = __expf(scal[3*g+1])*sc;
      float sdz = __expf(scal[3*g+2])*sc;
      float qr=rot[4*g+0], qx=rot[4*g+1], qy=rot[4*g+2], qz=rot[4*g+3];
      float qn = 1.0f/sqrtf(qr*qr+qx*qx+qy*qy+qz*qz);
      qr*=qn; qx*=qn; qy*=qn; qz*=qn;
      float R00 = 1.0f-2.0f*(qy*qy+qz*qz), R01 = 2.0f*(qx*qy-qr*qz), R02 = 2.0f*(qx*qz+qr*qy);
      float R10 = 2.0f*(qx*qy+qr*qz), R11 = 1.0f-2.0f*(qx*qx+qz*qz), R12 = 2.0f*(qy*qz-qr*qx);
      float R20 = 2.0f*(qx*qz-qr*qy), R21 = 2.0f*(qy*qz+qr*qx), R22 = 1.0f-2.0f*(qx*qx+qy*qy);
      float L00=R00*sdx, L01=R01*sdy, L02=R02*sdz;
      float L10=R10*sdx, L11=R11*sdy, L12=R12*sdz;
      float L20=R20*sdx, L21=R21*sdy, L22=R22*sdz;
      float a = L00*L00+L01*L01+L02*L02;
      float bb= L00*L10+L01*L11+L02*L12;
      float cc= L00*L20+L01*L21+L02*L22;
      float d = L10*L10+L11*L11+L12*L12;
      float e = L10*L20+L11*L21+L12*L22;
      float f = L20*L20+L21*L21+L22*L22;
      float det = a*d*f + 2.0f*e*cc*bb - e*e*a - cc*cc*d - bb*bb*f + 1e-24f;
      float idt = 1.0f/det;
      float ia=(d*f-e*e)*idt, ib=(e*cc-bb*f)*idt, ic=(e*bb-cc*d)*idt;
      float id=(a*f-cc*cc)*idt, ie=(bb*cc-e*a)*idt, iff=(a*d-bb*bb)*idt;
      int slot = atomicAdd(&s_cnt, 1);
      s_g[3*slot+0] = make_float4(xs, ys, zs, sig);
      s_g[3*slot+1] = make_float4(-0.5f*ia, -ib, -ic, -0.5f*id);
      s_g[3*slot+2] = make_float4(-ie, -0.5f*iff, 0.0f, 0.0f);
    }
    __syncthreads();
    const int n = s_cnt;
    #pragma unroll 4
    for (int j = part; j < n; j += 4) {
      float4 P  = s_g[3*j+0];
      float4 I0 = s_g[3*j+1];
      float4 I1 = s_g[3*j+2];
      float px = ptx - P.x, py = pty - P.y, pz = ptz - P.z;
      float power = px*px*I0.x + py*py*I0.w + pz*pz*I1.y
                  + px*py*I0.y + px*pz*I0.z + py*pz*I1.x;
      power = (power > 0.0f) ? -1e10f : power;
      acc += P.w * __expf(power);
    }
    __syncthreads();
    if (tid == 0) s_cnt = 0;
    __syncthreads();
  }
  s_acc[tid] = acc;
  __syncthreads();
  if (tid < 64) {
    float v = s_acc[tid] + s_acc[tid+64] + s_acc[tid+128] + s_acc[tid+192];
    out[(bi*4+sx)*4096 + (bj*4+sy)*64 + (bk*4+sz)] = v;
  }
}

extern "C" void kernel_launch(void* const* d_in, const int* in_sizes, int n_in,
                              void* d_out, int out_size, void* d_ws, size_t ws_size,
                              hipStream_t stream) {
  const float* xyz  = (const float*)d_in[0];
  const float* scal = (const float*)d_in[1];
  const float* rot  = (const float*)d_in[2];
  const float* opac = (const float*)d_in[3];
  float* out = (float*)d_out;
  char* ws = (char*)d_ws;
  float4* posopa = (float4*)(ws);               //  64 KB
  float4* invrec = (float4*)(ws + 65536);       // 128 KB

  if (ws_size >= 196608) {
    gm_prep<<<16, 256, 0, stream>>>(xyz, scal, rot, opac,
                                    posopa, invrec, (float4*)out);
    gm_eval<<<4096*SLICES, EV_THREADS, 0, stream>>>(posopa, invrec, out);
  } else {
    gm_fused_nows<<<4096, 256, 0, stream>>>(xyz, scal, rot, opac, out);
  }
}